// Round 10
// baseline (392.971 us; speedup 1.0000x reference)
//
#include <hip/hip_runtime.h>
#include <hip/hip_bf16.h>
#include <stdint.h>

#define M_DIM 8192
#define K_DIM 512
#define N_DIM 32000

typedef short bf16x8 __attribute__((ext_vector_type(8)));
typedef float f32x4 __attribute__((ext_vector_type(4)));
typedef unsigned short u16;

__device__ __forceinline__ u16 f2bf(float f) {
  union { float f; uint32_t u; } v; v.f = f;
  uint32_t r = (v.u + 0x7fffu + ((v.u >> 16) & 1u)) >> 16;  // RNE
  return (u16)r;
}

// ---------------- Kernel 0: zero the column-sumsq accumulator ----------------
__global__ void k_zero(float* __restrict__ cn) {
  cn[blockIdx.x * 256 + threadIdx.x] = 0.f;
}

// ---------------- Kernel 1: row-l2norm of x -> bf16, one wave per row ----------------
__global__ void k_xnorm(const float* __restrict__ x, u16* __restrict__ xn) {
  int row = (blockIdx.x * blockDim.x + threadIdx.x) >> 6;
  int lane = threadIdx.x & 63;
  const float4* rp = (const float4*)(x + (size_t)row * K_DIM);
  float4 a = rp[lane];
  float4 b = rp[lane + 64];
  float s = a.x*a.x + a.y*a.y + a.z*a.z + a.w*a.w
          + b.x*b.x + b.y*b.y + b.z*b.z + b.w*b.w;
#pragma unroll
  for (int off = 32; off > 0; off >>= 1) s += __shfl_xor(s, off, 64);
  float r = rsqrtf(fmaxf(s, 1e-12f));
  ushort4 o0 = make_ushort4(f2bf(a.x*r), f2bf(a.y*r), f2bf(a.z*r), f2bf(a.w*r));
  ushort4 o1 = make_ushort4(f2bf(b.x*r), f2bf(b.y*r), f2bf(b.z*r), f2bf(b.w*r));
  ushort4* dst = (ushort4*)(xn + (size_t)row * K_DIM);
  dst[lane] = o0;
  dst[lane + 64] = o1;
}

// ---------------- Kernel 2: transpose + cast (UNNORMALIZED) + fused col-sumsq ----------------
__global__ void k_wtrans(const float* __restrict__ w, float* __restrict__ cn,
                         u16* __restrict__ wT) {
  __shared__ u16 tile[64][68];
  int c0 = blockIdx.x * 64;
  int r0 = blockIdx.y * 64;
  int tc = threadIdx.x & 63;
  int tw = threadIdx.x >> 6;  // 0..3
  float s = 0.f;
#pragma unroll
  for (int i = 0; i < 16; ++i) {
    int r = i * 4 + tw;
    float v = w[(size_t)(r0 + r) * N_DIM + c0 + tc];
    s = fmaf(v, v, s);
    tile[tc][r] = f2bf(v);
  }
  atomicAdd(&cn[c0 + tc], s);
  __syncthreads();
  int cc = threadIdx.x >> 4;        // 0..15
  int rr = (threadIdx.x & 15) * 4;  // 0..60
#pragma unroll
  for (int i = 0; i < 4; ++i) {
    int c = cc + i * 16;
    ushort4 v = *(const ushort4*)&tile[c][rr];
    *(ushort4*)(wT + (size_t)(c0 + c) * K_DIM + r0 + rr) = v;
  }
}

// ---------------- Kernel 3: PERSISTENT XCD-BANDED 256x128 GEMM, BK=32, 2 blocks/CU ----------------
// 512 blocks = 2/CU (48 KiB LDS, ~210 VGPR). Tile 256(M)x128(N); 4 waves (2x2),
// each wave 128x64 (8m x 4n acc) -> 12 ds_read_b128 per 32 MFMA per kt (ratio
// 2.67, m201's per-wave shape) while KEEPING 2-block TLP. XCD (b&7) owns bm
// band [xcd*4, xcd*4+4); worker blk=b>>3: bm = xcd*4+(blk&3) FIXED, walks
// bn = (blk>>2) + 16*ti. Sibling blocks (blk, blk+32) share the same A panel.
__global__ __launch_bounds__(256, 2) void k_gemm(const u16* __restrict__ A,
                                                 const u16* __restrict__ Bt,
                                                 const float* __restrict__ cn,
                                                 float* __restrict__ C) {
  __shared__ u16 sm[2 * 12288];  // per buf (12288 elems): A [256][32] @0, B [128][32] @8192
  constexpr int BOFF = 8192;     // elems
  constexpr int BUFE = 12288;    // elems per buffer

  const int b = blockIdx.x;
  const int xcd = b & 7;
  const int blk = b >> 3;               // 0..63 worker within XCD
  const int bm = xcd * 4 + (blk & 3);   // FIXED per worker (32 bm tiles total)
  const int bn0 = blk >> 2;             // 0..15
  const int cnt = (bn0 < 10) ? 16 : 15; // bn = bn0 + 16*ti < 250

  const int tid = threadIdx.x;
  const int lane = tid & 63;
  const int w = tid >> 6;   // 0..3
  const int wr = w >> 1;    // 0..1 (128-row half)
  const int wc = w & 1;     // 0..1 (64-col half)
  const int la = lane & 15;
  const int lk = lane >> 4; // 0..3 = kk slot
  // read-side swizzle: slot' = lk ^ ((row>>1)&3); row = base+la with base%8==0
  const int sread = (lk ^ ((la >> 1) & 3)) * 8;  // elems

  // staging (rule #21): thread tid -> row tid>>2 (+i*64), logical slot tid&3.
  // Pre-swizzle global col by slot' = (tid&3) ^ ((row>>1)&3) = (tid&3)^((tid>>3)&3);
  // LDS dest stays LINEAR at tid*8 (+i*2048).
  const int srow = tid >> 2;
  const int sgl = ((tid & 3) ^ ((tid >> 3) & 3)) * 8;
  const int ldst = tid * 8;

  const u16* ag = A + (size_t)(bm * 256 + srow) * K_DIM + sgl;  // fixed all run
  int bn = bn0;
  const u16* bg = Bt + (size_t)(bn * 128 + srow) * K_DIM + sgl;
  constexpr size_t BSTEP = (size_t)16 * 128 * K_DIM;  // bn += 16

  const int arow0 = (wr * 128 + la) * 32;  // + m*512 (elems within A region)
  const int brow0 = (wc * 64 + la) * 32;   // + n*512 (elems within B region)

  f32x4 acc[8][4] = {};

#define GLL(p, eoff)                                                              \
  __builtin_amdgcn_global_load_lds(                                              \
      (const __attribute__((address_space(1))) void*)(p),                        \
      (__attribute__((address_space(3))) void*)&sm[(eoff)], 16, 0, 0)

  // prologue: stage (tile0, kt=0) into buf 0 (A: 4 instrs, B: 2)
#pragma unroll
  for (int i = 0; i < 4; ++i) GLL(ag + (size_t)i * 64 * K_DIM, i * 2048 + ldst);
#pragma unroll
  for (int i = 0; i < 2; ++i) GLL(bg + (size_t)i * 64 * K_DIM, BOFF + i * 2048 + ldst);
  __syncthreads();

  for (int ti = 0; ti < cnt; ++ti) {
    const bool last_tile = (ti + 1 == cnt);

    for (int kt = 0; kt < 16; ++kt) {
      const int cur = (kt & 1) * BUFE;
      const int nxt = cur ^ BUFE;
      const bool pf = (kt < 15) || !last_tile;
      const u16* agk = (kt < 15) ? (ag + (kt + 1) * 32) : ag;           // next tile: same A panel
      const u16* bgk = (kt < 15) ? (bg + (kt + 1) * 32) : (bg + BSTEP); // next tile: bn+16

      // stage next K-step (drained by the kt-end __syncthreads)
      if (pf) {
#pragma unroll
        for (int i = 0; i < 4; ++i) GLL(agk + (size_t)i * 64 * K_DIM, nxt + i * 2048 + ldst);
#pragma unroll
        for (int i = 0; i < 2; ++i) GLL(bgk + (size_t)i * 64 * K_DIM, nxt + BOFF + i * 2048 + ldst);
      }

      // fragments: 8 A + 4 B reads for 32 MFMA
      bf16x8 af[8], bf[4];
#pragma unroll
      for (int m = 0; m < 8; ++m)
        af[m] = *(const bf16x8*)&sm[cur + arow0 + m * 512 + sread];
#pragma unroll
      for (int n = 0; n < 4; ++n)
        bf[n] = *(const bf16x8*)&sm[cur + BOFF + brow0 + n * 512 + sread];

#pragma unroll
      for (int m = 0; m < 8; ++m)
#pragma unroll
        for (int n = 0; n < 4; ++n)
          acc[m][n] = __builtin_amdgcn_mfma_f32_16x16x32_bf16(af[m], bf[n], acc[m][n], 0, 0, 0);

      __syncthreads();  // buf[nxt] staged + all reads of buf[cur] done
    }

    // ---- tile epilogue: scale by rsqrt(col sumsq), fire-and-forget NT stores ----
    {
      const size_t crow0 = (size_t)bm * 256 + wr * 128 + lk * 4;
      const int ccol0 = bn * 128 + wc * 64 + la;
      float rs[4];
#pragma unroll
      for (int n = 0; n < 4; ++n)
        rs[n] = rsqrtf(fmaxf(cn[ccol0 + n * 16], 1e-12f));
#pragma unroll
      for (int m = 0; m < 8; ++m)
#pragma unroll
        for (int j = 0; j < 4; ++j) {
          float* cp = C + (crow0 + m * 16 + j) * N_DIM + ccol0;
#pragma unroll
          for (int n = 0; n < 4; ++n)
            __builtin_nontemporal_store(acc[m][n][j] * rs[n], cp + n * 16);
        }
#pragma unroll
      for (int m = 0; m < 8; ++m)
#pragma unroll
        for (int n = 0; n < 4; ++n)
          acc[m][n] = (f32x4){0.f, 0.f, 0.f, 0.f};
    }

    bn += 16;
    bg += BSTEP;
  }
#undef GLL
}

// ---------------- launch ----------------
extern "C" void kernel_launch(void* const* d_in, const int* in_sizes, int n_in,
                              void* d_out, int out_size, void* d_ws, size_t ws_size,
                              hipStream_t stream) {
  const float* x = (const float*)d_in[0];   // [8192, 512]
  const float* w = (const float*)d_in[1];   // [512, 32000]
  float* out = (float*)d_out;               // [8192, 32000]

  char* ws = (char*)d_ws;
  float* cn = (float*)ws;                                    // 32000 f32 (sumsq)
  u16* xn = (u16*)(ws + 131072);                             // 8192*512 bf16
  u16* wT = (u16*)(ws + 131072 + (size_t)M_DIM * K_DIM * 2); // 32000*512 bf16

  k_zero<<<N_DIM / 256, 256, 0, stream>>>(cn);
  k_xnorm<<<M_DIM / 4, 256, 0, stream>>>(x, xn);
  k_wtrans<<<dim3(N_DIM / 64, K_DIM / 64), 256, 0, stream>>>(w, cn, wT);
  k_gemm<<<512, 256, 0, stream>>>(xn, wT, cn, out);
}